// Round 3
// baseline (377.002 us; speedup 1.0000x reference)
//
#include <hip/hip_runtime.h>
#include <hip/hip_bf16.h>
#include <math.h>

// Problem constants
#define BATCH 64
#define CIN   32
#define TIN   2048
#define FILT  64
#define WIN   5
#define TP1   2044   // conv1 out
#define TP2   2040   // pool out
#define LOUT  2036   // conv2 out
#define DEMB  256
#define DA    64
#define NSEC  11
#define NC    4      // S chunks
#define CS    509    // l's per chunk (4*509 = 2036)
#define TILE_T 252   // h2 outputs per conv1 block

// ---------------------------------------------------------------------------
// Kernel P: fused prep — zero count, W1 transpose (LDS tile), emb transpose
// (LDS tile), w1 repack to [c][f][k]. Grid = 64 + 32 + 16 + 40 = 152 blocks.
// ---------------------------------------------------------------------------
__global__ __launch_bounds__(256) void k_prep(
    const float* __restrict__ W1, const float* __restrict__ emb,
    const float* __restrict__ w1, float* __restrict__ w1t,
    float* __restrict__ embT, float* __restrict__ w1r, int* __restrict__ count) {
  __shared__ float tl[64 * 65];
  int bk = blockIdx.x;
  const int tid = threadIdx.x;
  if (bk < 64) { count[bk * 256 + tid] = 0; return; }
  bk -= 64;
  if (bk < 32) {                       // W1 [64 x 2036] -> w1t [2036 x 64]
    const int l0 = bk * 64;
    const int lc = tid & 63, rq = tid >> 6;
    for (int a = rq; a < 64; a += 4)
      tl[a * 65 + lc] = (l0 + lc < LOUT) ? W1[a * LOUT + l0 + lc] : 0.f;
    __syncthreads();
    for (int lp = rq; lp < 64; lp += 4)
      if (l0 + lp < LOUT) w1t[(l0 + lp) * 64 + lc] = tl[lc * 65 + lp];
    return;
  }
  bk -= 32;
  if (bk < 16) {                       // emb [256 x 256] -> embT [256 x 256]
    const int j0 = (bk & 3) * 64, d0 = (bk >> 2) * 64;
    const int c = tid & 63, rq = tid >> 6;
    for (int j = rq; j < 64; j += 4) tl[j * 65 + c] = emb[(j0 + j) * DEMB + d0 + c];
    __syncthreads();
    for (int d = rq; d < 64; d += 4) embT[(d0 + d) * DEMB + j0 + c] = tl[c * 65 + d];
    return;
  }
  bk -= 16;
  {                                    // w1 [f][c][k] -> w1r [c][f*5+k]
    int i = bk * 256 + tid;            // 40*256 = 10240 exactly
    int c = i / 320, r = i - c * 320, f = r / 5, k = r - f * 5;
    w1r[i] = w1[f * (CIN * WIN) + c * WIN + k];
  }
}

// ---------------------------------------------------------------------------
// Kernel A: conv1 + bias + maxpool(5,1) + BN partials.
// Grid (9, 64, 2): z splits filters 0-31 / 32-63 -> 1152 blocks (4.5/CU).
// Wave handles 8 filters (acc[8][4] = 32 VGPR), lane covers 4 t positions.
// Weights from w1r [c][f][k]: 40 contiguous floats per (c, wave) -> wide s_load.
// ---------------------------------------------------------------------------
__global__ __launch_bounds__(256) void k_conv1pool(
    const float* __restrict__ x, const float* __restrict__ w1r,
    const float* __restrict__ b1, float* __restrict__ h2,
    float* __restrict__ bnps, float* __restrict__ bnpq) {
  __shared__ float xl[CIN * 264];
  const int b   = blockIdx.y;
  const int t0  = blockIdx.x * TILE_T;
  const int tid = threadIdx.x;

  for (int i = tid; i < CIN * 264; i += 256) {
    int c = i / 264, o = i - c * 264;
    int gt = t0 + o;
    float v = 0.f;
    if (o < 260 && gt < TIN) v = x[(b * CIN + c) * TIN + gt];
    xl[i] = v;
  }
  __syncthreads();

  const int tg  = tid & 63;
  const int tb  = tg * 4;
  const int wf0 = __builtin_amdgcn_readfirstlane((int)blockIdx.z * 32 + (tid >> 6) * 8);

  float acc[8][4];
#pragma unroll
  for (int ff = 0; ff < 8; ++ff) {
    float bias = b1[wf0 + ff];
    acc[ff][0] = bias; acc[ff][1] = bias; acc[ff][2] = bias; acc[ff][3] = bias;
  }

  for (int c = 0; c < CIN; ++c) {
    float4 xa  = *(const float4*)&xl[c * 264 + tb];
    float4 xb4 = *(const float4*)&xl[c * 264 + tb + 4];
    float xw[8] = {xa.x, xa.y, xa.z, xa.w, xb4.x, xb4.y, xb4.z, xb4.w};
    const float* wr = w1r + c * 320 + wf0 * 5;   // 40 contiguous floats, uniform
#pragma unroll
    for (int ff = 0; ff < 8; ++ff) {
#pragma unroll
      for (int k = 0; k < WIN; ++k) {
        float wv = wr[ff * 5 + k];
        acc[ff][0] = fmaf(xw[k + 0], wv, acc[ff][0]);
        acc[ff][1] = fmaf(xw[k + 1], wv, acc[ff][1]);
        acc[ff][2] = fmaf(xw[k + 2], wv, acc[ff][2]);
        acc[ff][3] = fmaf(xw[k + 3], wv, acc[ff][3]);
      }
    }
  }

  const bool rowvalid = (tg < 63);
  const int blk = b * 9 + blockIdx.x;
#pragma unroll
  for (int ff = 0; ff < 8; ++ff) {
    float n0 = __shfl_down(acc[ff][0], 1);
    float n1 = __shfl_down(acc[ff][1], 1);
    float n2 = __shfl_down(acc[ff][2], 1);
    float n3 = __shfl_down(acc[ff][3], 1);
    float h[8] = {acc[ff][0], acc[ff][1], acc[ff][2], acc[ff][3], n0, n1, n2, n3};
    float o0 = fmaxf(fmaxf(fmaxf(h[0], h[1]), fmaxf(h[2], h[3])), h[4]);
    float o1 = fmaxf(fmaxf(fmaxf(h[1], h[2]), fmaxf(h[3], h[4])), h[5]);
    float o2 = fmaxf(fmaxf(fmaxf(h[2], h[3]), fmaxf(h[4], h[5])), h[6]);
    float o3 = fmaxf(fmaxf(fmaxf(h[3], h[4]), fmaxf(h[5], h[6])), h[7]);
    const int f = wf0 + ff;
    float s = 0.f, q = 0.f;
    const int t2b = t0 + tb;
    if (rowvalid && (t2b + 3 < TP2)) {
      *(float4*)&h2[(b * FILT + f) * TP2 + t2b] = make_float4(o0, o1, o2, o3);
      s = o0 + o1 + o2 + o3;
      q = o0 * o0 + o1 * o1 + o2 * o2 + o3 * o3;
    } else if (rowvalid) {
      float ov[4] = {o0, o1, o2, o3};
#pragma unroll
      for (int j = 0; j < 4; ++j) {
        int t2 = t2b + j;
        if (t2 < TP2) { h2[(b * FILT + f) * TP2 + t2] = ov[j]; s += ov[j]; q += ov[j] * ov[j]; }
      }
    }
#pragma unroll
    for (int off = 32; off > 0; off >>= 1) {
      s += __shfl_down(s, off);
      q += __shfl_down(q, off);
    }
    if (tg == 0) { bnps[blk * FILT + f] = s; bnpq[blk * FILT + f] = q; }
  }
}

// ---------------------------------------------------------------------------
// Kernel B: BN finalize + fold into conv2 weights — FP64 (frozen: rsqrtf's
// ~1e-5 error caused ~50 bucket flips in R1). Now 256 thr: 4 groups x 64 f.
// ---------------------------------------------------------------------------
__global__ __launch_bounds__(256) void k_bnfin(
    const float* __restrict__ bnps, const float* __restrict__ bnpq,
    const float* __restrict__ gamma, const float* __restrict__ beta,
    const float* __restrict__ w2, const float* __restrict__ b2,
    double* __restrict__ ws2, double* __restrict__ c0p) {
  __shared__ double ls[4 * 64], lq[4 * 64];
  const int tid = threadIdx.x;
  const int f = tid & 63, g = tid >> 6;
  double s = 0.0, q = 0.0;
  for (int blk = g; blk < 576; blk += 4) {
    s += (double)bnps[blk * FILT + f];
    q += (double)bnpq[blk * FILT + f];
  }
  ls[g * 64 + f] = s; lq[g * 64 + f] = q;
  __syncthreads();
  if (tid < 64) {
    s = ls[tid] + ls[64 + tid] + ls[128 + tid] + ls[192 + tid];
    q = lq[tid] + lq[64 + tid] + lq[128 + tid] + lq[192 + tid];
    const double N = (double)(BATCH * TP2);
    double mu  = s / N;
    double var = q / N - mu * mu;
    double sc  = (double)gamma[tid] / sqrt(var + 1e-5);
    double sh  = (double)beta[tid] - mu * sc;
    double wsum = 0.0;
#pragma unroll
    for (int k = 0; k < WIN; ++k) {
      double wv = (double)w2[tid * WIN + k];
      ws2[tid * WIN + k] = sc * wv;
      wsum += wv;
    }
    double part = sh * wsum;
#pragma unroll
    for (int off = 32; off > 0; off >>= 1) part += __shfl_down(part, off);
    if (tid == 0) c0p[0] = part + (double)b2[0];
  }
}

// ---------------------------------------------------------------------------
// Kernel C: conv2 in FP64 + FP64 sigmoid/quantize + histogram. (frozen path)
// ---------------------------------------------------------------------------
__global__ __launch_bounds__(256) void k_conv2(
    const float* __restrict__ h2, const double* __restrict__ ws2,
    const double* __restrict__ c0p, int* __restrict__ idxp, int* __restrict__ count) {
  __shared__ float hl[FILT * 260];
  __shared__ int hist[DEMB];
  const int b = blockIdx.y;
  const int t0 = blockIdx.x * 256;
  const int tid = threadIdx.x;
  for (int i = tid; i < FILT * 260; i += 256) {
    int f = i / 260, o = i - f * 260;
    int gt = t0 + o;
    hl[i] = (gt < TP2) ? h2[(b * FILT + f) * TP2 + gt] : 0.f;
  }
  hist[tid] = 0;
  __syncthreads();
  const int t = t0 + tid;
  if (t < LOUT) {
    double z = c0p[0];
    for (int f = 0; f < FILT; ++f) {
      const double* wr = ws2 + f * WIN;
      z = fma((double)hl[f * 260 + tid + 0], wr[0], z);
      z = fma((double)hl[f * 260 + tid + 1], wr[1], z);
      z = fma((double)hl[f * 260 + tid + 2], wr[2], z);
      z = fma((double)hl[f * 260 + tid + 3], wr[3], z);
      z = fma((double)hl[f * 260 + tid + 4], wr[4], z);
    }
    z = z > 0.0 ? z : 0.0;
    double c = 1.0 / (1.0 + exp(-z));
    int iv = (int)ceil(c * 256.0) - 1;
    iv = min(max(iv, 0), DEMB - 1);
    idxp[b * LOUT + t] = iv;
    atomicAdd(&hist[iv], 1);
  }
  __syncthreads();
  atomicAdd(&count[b * DEMB + tid], hist[tid]);
}

// ---------------------------------------------------------------------------
// Kernel D: S[b,a,j] = sum_{l in chunk: idx[b,l]==j} W1[a,l]. (unchanged)
// ---------------------------------------------------------------------------
__global__ __launch_bounds__(256) void k_sbuild(
    const int* __restrict__ idxp, const float* __restrict__ w1t,
    float* __restrict__ Sg) {
  __shared__ float S[DA * 257];
  __shared__ int il[512];
  const int b = blockIdx.y, ch = blockIdx.x;
  const int tid = threadIdx.x;
  for (int i = tid; i < DA * 257; i += 256) S[i] = 0.f;
  const int l0 = ch * CS;
  for (int i = tid; i < CS; i += 256) il[i] = idxp[b * LOUT + l0 + i];
  __syncthreads();
  const int a = tid & 63, w = tid >> 6;
#pragma unroll 4
  for (int li = w; li < CS; li += 4) {
    int j = il[li];                          // wave-uniform broadcast
    float v = w1t[(l0 + li) * DA + a];       // coalesced 256B/wave
    atomicAdd(&S[a * 257 + j], v);
  }
  __syncthreads();
  for (int i = tid; i < DA * DEMB; i += 256) {
    int aa = i >> 8, j = i & 255;
    Sg[((b * NC + ch) * DA + aa) * DEMB + j] = S[aa * 257 + j];
  }
}

// ---------------------------------------------------------------------------
// Kernel E: fp32 GEMM T = (sum_ch S) @ emb256, epilogue A = sum_a W2 tanh(T).
// ---------------------------------------------------------------------------
__global__ __launch_bounds__(256) void k_gemmA(
    const float* __restrict__ Sg, const float* __restrict__ emb,
    const float* __restrict__ W2, float* __restrict__ Avec) {
  __shared__ float Al[16 * 64];
  __shared__ float Bl[16 * 64];
  __shared__ float red[16 * 64];
  const int b = blockIdx.x, c0 = blockIdx.y * 64;
  const int tid = threadIdx.x;
  const int tx = tid & 15, ty = tid >> 4;
  const int sa = tid >> 2, skq = (tid & 3) * 4;   // A staging map
  const int bk = tid >> 4, bseg = tid & 15;       // B staging map
  float acc[4][4] = {{0}};

  for (int kc = 0; kc < 16; ++kc) {
    const int kb = kc * 16;
    float4 v0 = *(const float4*)&Sg[((b * NC + 0) * DA + sa) * DEMB + kb + skq];
    float4 v1 = *(const float4*)&Sg[((b * NC + 1) * DA + sa) * DEMB + kb + skq];
    float4 v2 = *(const float4*)&Sg[((b * NC + 2) * DA + sa) * DEMB + kb + skq];
    float4 v3 = *(const float4*)&Sg[((b * NC + 3) * DA + sa) * DEMB + kb + skq];
    float4 sv = make_float4(v0.x + v1.x + v2.x + v3.x, v0.y + v1.y + v2.y + v3.y,
                            v0.z + v1.z + v2.z + v3.z, v0.w + v1.w + v2.w + v3.w);
    Al[(skq + 0) * 64 + sa] = sv.x;
    Al[(skq + 1) * 64 + sa] = sv.y;
    Al[(skq + 2) * 64 + sa] = sv.z;
    Al[(skq + 3) * 64 + sa] = sv.w;
    float4 e4 = *(const float4*)&emb[(kb + bk) * DEMB + c0 + bseg * 4];
    *(float4*)&Bl[bk * 64 + bseg * 4] = e4;
    __syncthreads();
#pragma unroll
    for (int k = 0; k < 16; ++k) {
      float4 av = *(const float4*)&Al[k * 64 + ty * 4];
      float4 bv = *(const float4*)&Bl[k * 64 + tx * 4];
      acc[0][0] = fmaf(av.x, bv.x, acc[0][0]); acc[0][1] = fmaf(av.x, bv.y, acc[0][1]);
      acc[0][2] = fmaf(av.x, bv.z, acc[0][2]); acc[0][3] = fmaf(av.x, bv.w, acc[0][3]);
      acc[1][0] = fmaf(av.y, bv.x, acc[1][0]); acc[1][1] = fmaf(av.y, bv.y, acc[1][1]);
      acc[1][2] = fmaf(av.y, bv.z, acc[1][2]); acc[1][3] = fmaf(av.y, bv.w, acc[1][3]);
      acc[2][0] = fmaf(av.z, bv.x, acc[2][0]); acc[2][1] = fmaf(av.z, bv.y, acc[2][1]);
      acc[2][2] = fmaf(av.z, bv.z, acc[2][2]); acc[2][3] = fmaf(av.z, bv.w, acc[2][3]);
      acc[3][0] = fmaf(av.w, bv.x, acc[3][0]); acc[3][1] = fmaf(av.w, bv.y, acc[3][1]);
      acc[3][2] = fmaf(av.w, bv.z, acc[3][2]); acc[3][3] = fmaf(av.w, bv.w, acc[3][3]);
    }
    __syncthreads();
  }
  float cs[4] = {0.f, 0.f, 0.f, 0.f};
#pragma unroll
  for (int r = 0; r < 4; ++r) {
    float wv = W2[ty * 4 + r];
#pragma unroll
    for (int j = 0; j < 4; ++j) cs[j] += tanhf(acc[r][j]) * wv;
  }
#pragma unroll
  for (int j = 0; j < 4; ++j) red[ty * 64 + tx * 4 + j] = cs[j];
  __syncthreads();
  if (tid < 64) {
    float s = 0.f;
#pragma unroll
    for (int q = 0; q < 16; ++q) s += red[q * 64 + tid];
    Avec[b * DEMB + c0 + tid] = s;
  }
}

// ---------------------------------------------------------------------------
// Kernel G: bucket softmax + scores + fused att gather (p stays in LDS).
// ---------------------------------------------------------------------------
__global__ __launch_bounds__(256) void k_att(
    const float* __restrict__ Avec, const float* __restrict__ embT,
    const int* __restrict__ count, const float* __restrict__ linw,
    const float* __restrict__ linb, const int* __restrict__ idxp,
    float* __restrict__ att, float* __restrict__ scores) {
  __shared__ float Al[DEMB];
  __shared__ float pl[DEMB];
  __shared__ float scratch[4];
  const int b = blockIdx.x, j = threadIdx.x;
  Al[j] = Avec[b * DEMB + j];
  __syncthreads();
  float dot = 0.f;
  for (int d = 0; d < DEMB; ++d) dot = fmaf(embT[d * DEMB + j], Al[d], dot);
  const int cnt = count[b * DEMB + j];
  float v = (cnt > 0) ? dot : -3.4e38f;
#pragma unroll
  for (int off = 32; off > 0; off >>= 1) v = fmaxf(v, __shfl_down(v, off));
  if ((j & 63) == 0) scratch[j >> 6] = v;
  __syncthreads();
  const float m = fmaxf(fmaxf(scratch[0], scratch[1]), fmaxf(scratch[2], scratch[3]));
  __syncthreads();
  float e = (cnt > 0) ? expf(dot - m) : 0.f;
  float zs = e * (float)cnt;
#pragma unroll
  for (int off = 32; off > 0; off >>= 1) zs += __shfl_down(zs, off);
  if ((j & 63) == 0) scratch[j >> 6] = zs;
  __syncthreads();
  const float Z = scratch[0] + scratch[1] + scratch[2] + scratch[3];
  pl[j] = (cnt > 0) ? e / Z : 0.f;
  __syncthreads();
  // fused gather: att[b,l] = pl[idx[b,l]]
  for (int l = j; l < LOUT; l += 256)
    att[b * LOUT + l] = pl[idxp[b * LOUT + l]];
  // scores = A . lin_w^T + lin_b
  for (int s = 0; s < NSEC; ++s) {
    __syncthreads();
    float part = Al[j] * linw[s * DEMB + j];
#pragma unroll
    for (int off = 32; off > 0; off >>= 1) part += __shfl_down(part, off);
    if ((j & 63) == 0) scratch[j >> 6] = part;
    __syncthreads();
    if (j == 0)
      scores[b * NSEC + s] = scratch[0] + scratch[1] + scratch[2] + scratch[3] + linb[s];
  }
}

// ---------------------------------------------------------------------------
extern "C" void kernel_launch(void* const* d_in, const int* in_sizes, int n_in,
                              void* d_out, int out_size, void* d_ws, size_t ws_size,
                              hipStream_t stream) {
  const float* x      = (const float*)d_in[0];
  const float* w1     = (const float*)d_in[1];
  const float* b1     = (const float*)d_in[2];
  const float* gamma  = (const float*)d_in[3];
  const float* beta   = (const float*)d_in[4];
  const float* w2     = (const float*)d_in[5];
  const float* b2     = (const float*)d_in[6];
  const float* emb    = (const float*)d_in[7];
  const float* W1     = (const float*)d_in[8];
  const float* W2     = (const float*)d_in[9];
  const float* linw   = (const float*)d_in[10];
  const float* linb   = (const float*)d_in[11];

  char* ws = (char*)d_ws;
  int*    count = (int*)   (ws + 0);           // 65536
  double* ws2   = (double*)(ws + 65536);       // -> 68096
  double* c0p   = (double*)(ws + 68096);       // -> 68608 (padded)
  float*  bnps  = (float*) (ws + 68608);       // -> 216064
  float*  bnpq  = (float*) (ws + 216064);      // -> 363520
  int*    idxp  = (int*)   (ws + 363520);      // -> 884736
  float*  w1t   = (float*) (ws + 884736);      // -> 1405952
  float*  embT  = (float*) (ws + 1405952);     // -> 1668096
  float*  Avec  = (float*) (ws + 1668096);     // -> 1733632
  float*  w1r   = (float*) (ws + 1733632);     // -> 1774592
  float*  h2    = (float*) (ws + 1774592);     // -> 35197952
  float*  Sg    = (float*) (ws + 35197952);    // -> 51975168

  float* att_out    = (float*)d_out;
  float* scores_out = (float*)d_out + BATCH * LOUT;

  k_prep<<<dim3(152), 256, 0, stream>>>(W1, emb, w1, w1t, embT, w1r, count);
  k_conv1pool<<<dim3(9, 64, 2), 256, 0, stream>>>(x, w1r, b1, h2, bnps, bnpq);
  k_bnfin<<<dim3(1), 256, 0, stream>>>(bnps, bnpq, gamma, beta, w2, b2, ws2, c0p);
  k_conv2<<<dim3(8, 64), 256, 0, stream>>>(h2, ws2, c0p, idxp, count);
  k_sbuild<<<dim3(NC, 64), 256, 0, stream>>>(idxp, w1t, Sg);
  k_gemmA<<<dim3(64, 4), 256, 0, stream>>>(Sg, emb, W2, Avec);
  k_att<<<dim3(64), 256, 0, stream>>>(Avec, embT, count, linw, linb, idxp,
                                      att_out, scores_out);
}

// Round 4
// 368.162 us; speedup vs baseline: 1.0240x; 1.0240x over previous
//
#include <hip/hip_runtime.h>
#include <hip/hip_bf16.h>
#include <math.h>

// Problem constants
#define BATCH 64
#define CIN   32
#define TIN   2048
#define FILT  64
#define WIN   5
#define TP1   2044   // conv1 out
#define TP2   2040   // pool out
#define LOUT  2036   // conv2 out
#define DEMB  256
#define DA    64
#define NSEC  11
#define NC    4      // S chunks
#define CS    509    // l's per chunk (4*509 = 2036)
#define TILE_T 252   // h2 outputs per conv1 block

// ---------------------------------------------------------------------------
// Kernel P: fused prep — zero count, W1 transpose (LDS tile), emb transpose
// (LDS tile), w1 repack to [c][f][k]. Grid = 64 + 32 + 16 + 40 = 152 blocks.
// ---------------------------------------------------------------------------
__global__ __launch_bounds__(256) void k_prep(
    const float* __restrict__ W1, const float* __restrict__ emb,
    const float* __restrict__ w1, float* __restrict__ w1t,
    float* __restrict__ embT, float* __restrict__ w1r, int* __restrict__ count) {
  __shared__ float tl[64 * 65];
  int bk = blockIdx.x;
  const int tid = threadIdx.x;
  if (bk < 64) { count[bk * 256 + tid] = 0; return; }
  bk -= 64;
  if (bk < 32) {                       // W1 [64 x 2036] -> w1t [2036 x 64]
    const int l0 = bk * 64;
    const int lc = tid & 63, rq = tid >> 6;
    for (int a = rq; a < 64; a += 4)
      tl[a * 65 + lc] = (l0 + lc < LOUT) ? W1[a * LOUT + l0 + lc] : 0.f;
    __syncthreads();
    for (int lp = rq; lp < 64; lp += 4)
      if (l0 + lp < LOUT) w1t[(l0 + lp) * 64 + lc] = tl[lc * 65 + lp];
    return;
  }
  bk -= 32;
  if (bk < 16) {                       // emb [256 x 256] -> embT [256 x 256]
    const int j0 = (bk & 3) * 64, d0 = (bk >> 2) * 64;
    const int c = tid & 63, rq = tid >> 6;
    for (int j = rq; j < 64; j += 4) tl[j * 65 + c] = emb[(j0 + j) * DEMB + d0 + c];
    __syncthreads();
    for (int d = rq; d < 64; d += 4) embT[(d0 + d) * DEMB + j0 + c] = tl[c * 65 + d];
    return;
  }
  bk -= 16;
  {                                    // w1 [f][c][k] -> w1r [c][f*5+k]
    int i = bk * 256 + tid;            // 40*256 = 10240 exactly
    int c = i / 320, r = i - c * 320, f = r / 5, k = r - f * 5;
    w1r[i] = w1[f * (CIN * WIN) + c * WIN + k];
  }
}

// ---------------------------------------------------------------------------
// Kernel A: conv1 + bias + maxpool(5,1) + BN partials. R4 restructure:
//  - weights staged ONCE to LDS [c][160] per z-half; per-c the wave reads its
//    40-float slice via 10 ds_read_b128 BROADCASTS (same addr = conflict-free)
//    -> weights live in VGPRs, zero scalar loads in the hot loop.
//  - x read directly from global (2 dense coalesced b128/lane/c); no x tile,
//    no barrier in main loop; LDS 20KB -> whole grid co-resident (~5 blk/CU).
// Grid (9, 64, 2): z splits filters 0-31 / 32-63.
// ---------------------------------------------------------------------------
__global__ __launch_bounds__(256) void k_conv1pool(
    const float* __restrict__ x, const float* __restrict__ w1r,
    const float* __restrict__ b1, float* __restrict__ h2,
    float* __restrict__ bnps, float* __restrict__ bnpq) {
  __shared__ float wl[CIN * 160];
  const int b   = blockIdx.y;
  const int t0  = blockIdx.x * TILE_T;
  const int tid = threadIdx.x;
  const int z   = blockIdx.z;

  for (int i = tid; i < CIN * 160; i += 256) {
    int c = i / 160, r = i - c * 160;
    wl[i] = w1r[c * 320 + z * 160 + r];
  }
  __syncthreads();

  const int tg   = tid & 63;
  const int tb   = tg * 4;
  const int wv40 = (tid >> 6) * 40;
  const int wf0  = __builtin_amdgcn_readfirstlane(z * 32 + (tid >> 6) * 8);

  float acc[8][4];
#pragma unroll
  for (int ff = 0; ff < 8; ++ff) {
    float bias = b1[wf0 + ff];
    acc[ff][0] = bias; acc[ff][1] = bias; acc[ff][2] = bias; acc[ff][3] = bias;
  }

  const float* xrow = x + (size_t)b * CIN * TIN + t0 + tb;
  const bool safe = (t0 + tb + 8) <= TIN;

  for (int c = 0; c < CIN; ++c) {
    float xw[8];
    if (safe) {
      float4 xa = *(const float4*)(xrow + c * TIN);
      float4 xb = *(const float4*)(xrow + c * TIN + 4);
      xw[0] = xa.x; xw[1] = xa.y; xw[2] = xa.z; xw[3] = xa.w;
      xw[4] = xb.x; xw[5] = xb.y; xw[6] = xb.z; xw[7] = xb.w;
    } else {
#pragma unroll
      for (int j = 0; j < 8; ++j) {
        int gt = t0 + tb + j;
        xw[j] = (gt < TIN) ? xrow[c * TIN + j] : 0.f;
      }
    }
    float wa[40];
#pragma unroll
    for (int q = 0; q < 10; ++q) {
      float4 wq = *(const float4*)&wl[c * 160 + wv40 + q * 4];
      wa[q * 4 + 0] = wq.x; wa[q * 4 + 1] = wq.y;
      wa[q * 4 + 2] = wq.z; wa[q * 4 + 3] = wq.w;
    }
#pragma unroll
    for (int ff = 0; ff < 8; ++ff) {
#pragma unroll
      for (int k = 0; k < WIN; ++k) {
        float wv = wa[ff * 5 + k];
        acc[ff][0] = fmaf(xw[k + 0], wv, acc[ff][0]);
        acc[ff][1] = fmaf(xw[k + 1], wv, acc[ff][1]);
        acc[ff][2] = fmaf(xw[k + 2], wv, acc[ff][2]);
        acc[ff][3] = fmaf(xw[k + 3], wv, acc[ff][3]);
      }
    }
  }

  const bool rowvalid = (tg < 63);
  const int blk = b * 9 + blockIdx.x;
#pragma unroll
  for (int ff = 0; ff < 8; ++ff) {
    float n0 = __shfl_down(acc[ff][0], 1);
    float n1 = __shfl_down(acc[ff][1], 1);
    float n2 = __shfl_down(acc[ff][2], 1);
    float n3 = __shfl_down(acc[ff][3], 1);
    float h[8] = {acc[ff][0], acc[ff][1], acc[ff][2], acc[ff][3], n0, n1, n2, n3};
    float o0 = fmaxf(fmaxf(fmaxf(h[0], h[1]), fmaxf(h[2], h[3])), h[4]);
    float o1 = fmaxf(fmaxf(fmaxf(h[1], h[2]), fmaxf(h[3], h[4])), h[5]);
    float o2 = fmaxf(fmaxf(fmaxf(h[2], h[3]), fmaxf(h[4], h[5])), h[6]);
    float o3 = fmaxf(fmaxf(fmaxf(h[3], h[4]), fmaxf(h[5], h[6])), h[7]);
    const int f = wf0 + ff;
    float s = 0.f, q = 0.f;
    const int t2b = t0 + tb;
    if (rowvalid && (t2b + 3 < TP2)) {
      *(float4*)&h2[((size_t)b * FILT + f) * TP2 + t2b] = make_float4(o0, o1, o2, o3);
      s = o0 + o1 + o2 + o3;
      q = o0 * o0 + o1 * o1 + o2 * o2 + o3 * o3;
    } else if (rowvalid) {
      float ov[4] = {o0, o1, o2, o3};
#pragma unroll
      for (int j = 0; j < 4; ++j) {
        int t2 = t2b + j;
        if (t2 < TP2) { h2[((size_t)b * FILT + f) * TP2 + t2] = ov[j]; s += ov[j]; q += ov[j] * ov[j]; }
      }
    }
#pragma unroll
    for (int off = 32; off > 0; off >>= 1) {
      s += __shfl_down(s, off);
      q += __shfl_down(q, off);
    }
    if (tg == 0) { bnps[blk * FILT + f] = s; bnpq[blk * FILT + f] = q; }
  }
}

// ---------------------------------------------------------------------------
// Kernel B: BN finalize + fold into conv2 weights — FP64 (frozen: rsqrtf's
// ~1e-5 error caused ~50 bucket flips in R1). 256 thr: 4 groups x 64 f.
// ---------------------------------------------------------------------------
__global__ __launch_bounds__(256) void k_bnfin(
    const float* __restrict__ bnps, const float* __restrict__ bnpq,
    const float* __restrict__ gamma, const float* __restrict__ beta,
    const float* __restrict__ w2, const float* __restrict__ b2,
    double* __restrict__ ws2, double* __restrict__ c0p) {
  __shared__ double ls[4 * 64], lq[4 * 64];
  const int tid = threadIdx.x;
  const int f = tid & 63, g = tid >> 6;
  double s = 0.0, q = 0.0;
  for (int blk = g; blk < 576; blk += 4) {
    s += (double)bnps[blk * FILT + f];
    q += (double)bnpq[blk * FILT + f];
  }
  ls[g * 64 + f] = s; lq[g * 64 + f] = q;
  __syncthreads();
  if (tid < 64) {
    s = ls[tid] + ls[64 + tid] + ls[128 + tid] + ls[192 + tid];
    q = lq[tid] + lq[64 + tid] + lq[128 + tid] + lq[192 + tid];
    const double N = (double)(BATCH * TP2);
    double mu  = s / N;
    double var = q / N - mu * mu;
    double sc  = (double)gamma[tid] / sqrt(var + 1e-5);
    double sh  = (double)beta[tid] - mu * sc;
    double wsum = 0.0;
#pragma unroll
    for (int k = 0; k < WIN; ++k) {
      double wv = (double)w2[tid * WIN + k];
      ws2[tid * WIN + k] = sc * wv;
      wsum += wv;
    }
    double part = sh * wsum;
#pragma unroll
    for (int off = 32; off > 0; off >>= 1) part += __shfl_down(part, off);
    if (tid == 0) c0p[0] = part + (double)b2[0];
  }
}

// ---------------------------------------------------------------------------
// Kernel C: conv2 in FP64 + FP64 sigmoid/quantize + histogram. (frozen path)
// ---------------------------------------------------------------------------
__global__ __launch_bounds__(256) void k_conv2(
    const float* __restrict__ h2, const double* __restrict__ ws2,
    const double* __restrict__ c0p, int* __restrict__ idxp, int* __restrict__ count) {
  __shared__ float hl[FILT * 260];
  __shared__ int hist[DEMB];
  const int b = blockIdx.y;
  const int t0 = blockIdx.x * 256;
  const int tid = threadIdx.x;
  for (int i = tid; i < FILT * 260; i += 256) {
    int f = i / 260, o = i - f * 260;
    int gt = t0 + o;
    hl[i] = (gt < TP2) ? h2[((size_t)b * FILT + f) * TP2 + gt] : 0.f;
  }
  hist[tid] = 0;
  __syncthreads();
  const int t = t0 + tid;
  if (t < LOUT) {
    double z = c0p[0];
    for (int f = 0; f < FILT; ++f) {
      const double* wr = ws2 + f * WIN;
      z = fma((double)hl[f * 260 + tid + 0], wr[0], z);
      z = fma((double)hl[f * 260 + tid + 1], wr[1], z);
      z = fma((double)hl[f * 260 + tid + 2], wr[2], z);
      z = fma((double)hl[f * 260 + tid + 3], wr[3], z);
      z = fma((double)hl[f * 260 + tid + 4], wr[4], z);
    }
    z = z > 0.0 ? z : 0.0;
    double c = 1.0 / (1.0 + exp(-z));
    int iv = (int)ceil(c * 256.0) - 1;
    iv = min(max(iv, 0), DEMB - 1);
    idxp[b * LOUT + t] = iv;
    atomicAdd(&hist[iv], 1);
  }
  __syncthreads();
  atomicAdd(&count[b * DEMB + tid], hist[tid]);
}

// ---------------------------------------------------------------------------
// Kernel D: S[b,a,j] = sum_{l in chunk: idx[b,l]==j} W1[a,l]. (unchanged)
// ---------------------------------------------------------------------------
__global__ __launch_bounds__(256) void k_sbuild(
    const int* __restrict__ idxp, const float* __restrict__ w1t,
    float* __restrict__ Sg) {
  __shared__ float S[DA * 257];
  __shared__ int il[512];
  const int b = blockIdx.y, ch = blockIdx.x;
  const int tid = threadIdx.x;
  for (int i = tid; i < DA * 257; i += 256) S[i] = 0.f;
  const int l0 = ch * CS;
  for (int i = tid; i < CS; i += 256) il[i] = idxp[b * LOUT + l0 + i];
  __syncthreads();
  const int a = tid & 63, w = tid >> 6;
#pragma unroll 4
  for (int li = w; li < CS; li += 4) {
    int j = il[li];                          // wave-uniform broadcast
    float v = w1t[(l0 + li) * DA + a];       // coalesced 256B/wave
    atomicAdd(&S[a * 257 + j], v);
  }
  __syncthreads();
  for (int i = tid; i < DA * DEMB; i += 256) {
    int aa = i >> 8, j = i & 255;
    Sg[((b * NC + ch) * DA + aa) * DEMB + j] = S[aa * 257 + j];
  }
}

// ---------------------------------------------------------------------------
// Kernel E: fp32 GEMM T = (sum_ch S) @ emb256, epilogue A = sum_a W2 tanh(T).
// ---------------------------------------------------------------------------
__global__ __launch_bounds__(256) void k_gemmA(
    const float* __restrict__ Sg, const float* __restrict__ emb,
    const float* __restrict__ W2, float* __restrict__ Avec) {
  __shared__ float Al[16 * 64];
  __shared__ float Bl[16 * 64];
  __shared__ float red[16 * 64];
  const int b = blockIdx.x, c0 = blockIdx.y * 64;
  const int tid = threadIdx.x;
  const int tx = tid & 15, ty = tid >> 4;
  const int sa = tid >> 2, skq = (tid & 3) * 4;   // A staging map
  const int bk = tid >> 4, bseg = tid & 15;       // B staging map
  float acc[4][4] = {{0}};

  for (int kc = 0; kc < 16; ++kc) {
    const int kb = kc * 16;
    float4 v0 = *(const float4*)&Sg[((b * NC + 0) * DA + sa) * DEMB + kb + skq];
    float4 v1 = *(const float4*)&Sg[((b * NC + 1) * DA + sa) * DEMB + kb + skq];
    float4 v2 = *(const float4*)&Sg[((b * NC + 2) * DA + sa) * DEMB + kb + skq];
    float4 v3 = *(const float4*)&Sg[((b * NC + 3) * DA + sa) * DEMB + kb + skq];
    float4 sv = make_float4(v0.x + v1.x + v2.x + v3.x, v0.y + v1.y + v2.y + v3.y,
                            v0.z + v1.z + v2.z + v3.z, v0.w + v1.w + v2.w + v3.w);
    Al[(skq + 0) * 64 + sa] = sv.x;
    Al[(skq + 1) * 64 + sa] = sv.y;
    Al[(skq + 2) * 64 + sa] = sv.z;
    Al[(skq + 3) * 64 + sa] = sv.w;
    float4 e4 = *(const float4*)&emb[(kb + bk) * DEMB + c0 + bseg * 4];
    *(float4*)&Bl[bk * 64 + bseg * 4] = e4;
    __syncthreads();
#pragma unroll
    for (int k = 0; k < 16; ++k) {
      float4 av = *(const float4*)&Al[k * 64 + ty * 4];
      float4 bv = *(const float4*)&Bl[k * 64 + tx * 4];
      acc[0][0] = fmaf(av.x, bv.x, acc[0][0]); acc[0][1] = fmaf(av.x, bv.y, acc[0][1]);
      acc[0][2] = fmaf(av.x, bv.z, acc[0][2]); acc[0][3] = fmaf(av.x, bv.w, acc[0][3]);
      acc[1][0] = fmaf(av.y, bv.x, acc[1][0]); acc[1][1] = fmaf(av.y, bv.y, acc[1][1]);
      acc[1][2] = fmaf(av.y, bv.z, acc[1][2]); acc[1][3] = fmaf(av.y, bv.w, acc[1][3]);
      acc[2][0] = fmaf(av.z, bv.x, acc[2][0]); acc[2][1] = fmaf(av.z, bv.y, acc[2][1]);
      acc[2][2] = fmaf(av.z, bv.z, acc[2][2]); acc[2][3] = fmaf(av.z, bv.w, acc[2][3]);
      acc[3][0] = fmaf(av.w, bv.x, acc[3][0]); acc[3][1] = fmaf(av.w, bv.y, acc[3][1]);
      acc[3][2] = fmaf(av.w, bv.z, acc[3][2]); acc[3][3] = fmaf(av.w, bv.w, acc[3][3]);
    }
    __syncthreads();
  }
  float cs[4] = {0.f, 0.f, 0.f, 0.f};
#pragma unroll
  for (int r = 0; r < 4; ++r) {
    float wv = W2[ty * 4 + r];
#pragma unroll
    for (int j = 0; j < 4; ++j) cs[j] += tanhf(acc[r][j]) * wv;
  }
#pragma unroll
  for (int j = 0; j < 4; ++j) red[ty * 64 + tx * 4 + j] = cs[j];
  __syncthreads();
  if (tid < 64) {
    float s = 0.f;
#pragma unroll
    for (int q = 0; q < 16; ++q) s += red[q * 64 + tid];
    Avec[b * DEMB + c0 + tid] = s;
  }
}

// ---------------------------------------------------------------------------
// Kernel G: bucket softmax + scores + fused att gather (p stays in LDS).
// ---------------------------------------------------------------------------
__global__ __launch_bounds__(256) void k_att(
    const float* __restrict__ Avec, const float* __restrict__ embT,
    const int* __restrict__ count, const float* __restrict__ linw,
    const float* __restrict__ linb, const int* __restrict__ idxp,
    float* __restrict__ att, float* __restrict__ scores) {
  __shared__ float Al[DEMB];
  __shared__ float pl[DEMB];
  __shared__ float scratch[4];
  const int b = blockIdx.x, j = threadIdx.x;
  Al[j] = Avec[b * DEMB + j];
  __syncthreads();
  float dot = 0.f;
  for (int d = 0; d < DEMB; ++d) dot = fmaf(embT[d * DEMB + j], Al[d], dot);
  const int cnt = count[b * DEMB + j];
  float v = (cnt > 0) ? dot : -3.4e38f;
#pragma unroll
  for (int off = 32; off > 0; off >>= 1) v = fmaxf(v, __shfl_down(v, off));
  if ((j & 63) == 0) scratch[j >> 6] = v;
  __syncthreads();
  const float m = fmaxf(fmaxf(scratch[0], scratch[1]), fmaxf(scratch[2], scratch[3]));
  __syncthreads();
  float e = (cnt > 0) ? expf(dot - m) : 0.f;
  float zs = e * (float)cnt;
#pragma unroll
  for (int off = 32; off > 0; off >>= 1) zs += __shfl_down(zs, off);
  if ((j & 63) == 0) scratch[j >> 6] = zs;
  __syncthreads();
  const float Z = scratch[0] + scratch[1] + scratch[2] + scratch[3];
  pl[j] = (cnt > 0) ? e / Z : 0.f;
  __syncthreads();
  for (int l = j; l < LOUT; l += 256)
    att[b * LOUT + l] = pl[idxp[b * LOUT + l]];
  for (int s = 0; s < NSEC; ++s) {
    __syncthreads();
    float part = Al[j] * linw[s * DEMB + j];
#pragma unroll
    for (int off = 32; off > 0; off >>= 1) part += __shfl_down(part, off);
    if ((j & 63) == 0) scratch[j >> 6] = part;
    __syncthreads();
    if (j == 0)
      scores[b * NSEC + s] = scratch[0] + scratch[1] + scratch[2] + scratch[3] + linb[s];
  }
}

// ---------------------------------------------------------------------------
extern "C" void kernel_launch(void* const* d_in, const int* in_sizes, int n_in,
                              void* d_out, int out_size, void* d_ws, size_t ws_size,
                              hipStream_t stream) {
  const float* x      = (const float*)d_in[0];
  const float* w1     = (const float*)d_in[1];
  const float* b1     = (const float*)d_in[2];
  const float* gamma  = (const float*)d_in[3];
  const float* beta   = (const float*)d_in[4];
  const float* w2     = (const float*)d_in[5];
  const float* b2     = (const float*)d_in[6];
  const float* emb    = (const float*)d_in[7];
  const float* W1     = (const float*)d_in[8];
  const float* W2     = (const float*)d_in[9];
  const float* linw   = (const float*)d_in[10];
  const float* linb   = (const float*)d_in[11];

  char* ws = (char*)d_ws;
  int*    count = (int*)   (ws + 0);           // 65536
  double* ws2   = (double*)(ws + 65536);       // -> 68096
  double* c0p   = (double*)(ws + 68096);       // -> 68608 (padded)
  float*  bnps  = (float*) (ws + 68608);       // -> 216064
  float*  bnpq  = (float*) (ws + 216064);      // -> 363520
  int*    idxp  = (int*)   (ws + 363520);      // -> 884736
  float*  w1t   = (float*) (ws + 884736);      // -> 1405952
  float*  embT  = (float*) (ws + 1405952);     // -> 1668096
  float*  Avec  = (float*) (ws + 1668096);     // -> 1733632
  float*  w1r   = (float*) (ws + 1733632);     // -> 1774592
  float*  h2    = (float*) (ws + 1774592);     // -> 35197952
  float*  Sg    = (float*) (ws + 35197952);    // -> 51975168

  float* att_out    = (float*)d_out;
  float* scores_out = (float*)d_out + BATCH * LOUT;

  k_prep<<<dim3(152), 256, 0, stream>>>(W1, emb, w1, w1t, embT, w1r, count);
  k_conv1pool<<<dim3(9, 64, 2), 256, 0, stream>>>(x, w1r, b1, h2, bnps, bnpq);
  k_bnfin<<<dim3(1), 256, 0, stream>>>(bnps, bnpq, gamma, beta, w2, b2, ws2, c0p);
  k_conv2<<<dim3(8, 64), 256, 0, stream>>>(h2, ws2, c0p, idxp, count);
  k_sbuild<<<dim3(NC, 64), 256, 0, stream>>>(idxp, w1t, Sg);
  k_gemmA<<<dim3(64, 4), 256, 0, stream>>>(Sg, emb, W2, Avec);
  k_att<<<dim3(64), 256, 0, stream>>>(Avec, embT, count, linw, linb, idxp,
                                      att_out, scores_out);
}

// Round 5
// 346.232 us; speedup vs baseline: 1.0889x; 1.0633x over previous
//
#include <hip/hip_runtime.h>
#include <hip/hip_bf16.h>
#include <math.h>

// Problem constants
#define BATCH 64
#define CIN   32
#define TIN   2048
#define FILT  64
#define WIN   5
#define TP1   2044   // conv1 out
#define TP2   2040   // pool out
#define LOUT  2036   // conv2 out
#define DEMB  256
#define DA    64
#define NSEC  11
#define NC    4      // S chunks
#define CS    509    // l's per chunk (4*509 = 2036)
#define TILE_T 252   // h2 outputs per conv1 block

// ---------------------------------------------------------------------------
// Kernel P: fused prep — zero count, W1 transpose, emb transpose, w1 repack.
// ---------------------------------------------------------------------------
__global__ __launch_bounds__(256) void k_prep(
    const float* __restrict__ W1, const float* __restrict__ emb,
    const float* __restrict__ w1, float* __restrict__ w1t,
    float* __restrict__ embT, float* __restrict__ w1r, int* __restrict__ count) {
  __shared__ float tl[64 * 65];
  int bk = blockIdx.x;
  const int tid = threadIdx.x;
  if (bk < 64) { count[bk * 256 + tid] = 0; return; }
  bk -= 64;
  if (bk < 32) {                       // W1 [64 x 2036] -> w1t [2036 x 64]
    const int l0 = bk * 64;
    const int lc = tid & 63, rq = tid >> 6;
    for (int a = rq; a < 64; a += 4)
      tl[a * 65 + lc] = (l0 + lc < LOUT) ? W1[a * LOUT + l0 + lc] : 0.f;
    __syncthreads();
    for (int lp = rq; lp < 64; lp += 4)
      if (l0 + lp < LOUT) w1t[(l0 + lp) * 64 + lc] = tl[lc * 65 + lp];
    return;
  }
  bk -= 32;
  if (bk < 16) {                       // emb [256 x 256] -> embT [256 x 256]
    const int j0 = (bk & 3) * 64, d0 = (bk >> 2) * 64;
    const int c = tid & 63, rq = tid >> 6;
    for (int j = rq; j < 64; j += 4) tl[j * 65 + c] = emb[(j0 + j) * DEMB + d0 + c];
    __syncthreads();
    for (int d = rq; d < 64; d += 4) embT[(d0 + d) * DEMB + j0 + c] = tl[c * 65 + d];
    return;
  }
  bk -= 16;
  {                                    // w1 [f][c][k] -> w1r [c][f*5+k]
    int i = bk * 256 + tid;            // 40*256 = 10240 exactly
    int c = i / 320, r = i - c * 320, f = r / 5, k = r - f * 5;
    w1r[i] = w1[f * (CIN * WIN) + c * WIN + k];
  }
}

// ---------------------------------------------------------------------------
// Kernel A: conv1 + bias + maxpool(5,1). R5: BN-partial epilogue DELETED
// (stats now computed from h2 by k_bnstat — removes ~128 ds_bpermute/thread
// serial tail). Explicit x prefetch: load c+1 while FMA'ing c.
// Weights in LDS, read as wave-broadcast b128 (conflict-free, R4-verified).
// Grid (9, 64, 2).
// ---------------------------------------------------------------------------
__global__ __launch_bounds__(256) void k_conv1pool(
    const float* __restrict__ x, const float* __restrict__ w1r,
    const float* __restrict__ b1, float* __restrict__ h2) {
  __shared__ float wl[CIN * 160];
  const int b   = blockIdx.y;
  const int t0  = blockIdx.x * TILE_T;
  const int tid = threadIdx.x;
  const int z   = blockIdx.z;

  for (int i = tid; i < CIN * 160; i += 256) {
    int c = i / 160, r = i - c * 160;
    wl[i] = w1r[c * 320 + z * 160 + r];
  }
  __syncthreads();

  const int tg   = tid & 63;
  const int tb   = tg * 4;
  const int wv40 = (tid >> 6) * 40;
  const int wf0  = __builtin_amdgcn_readfirstlane(z * 32 + (tid >> 6) * 8);

  float acc[8][4];
#pragma unroll
  for (int ff = 0; ff < 8; ++ff) {
    float bias = b1[wf0 + ff];
    acc[ff][0] = bias; acc[ff][1] = bias; acc[ff][2] = bias; acc[ff][3] = bias;
  }

  const float* xrow = x + (size_t)b * CIN * TIN + t0 + tb;
  const bool safe = (t0 + tb + 8) <= TIN;

  auto load_x = [&](int c, float* v) {
    if (safe) {
      float4 a  = *(const float4*)(xrow + c * TIN);
      float4 bq = *(const float4*)(xrow + c * TIN + 4);
      v[0] = a.x;  v[1] = a.y;  v[2] = a.z;  v[3] = a.w;
      v[4] = bq.x; v[5] = bq.y; v[6] = bq.z; v[7] = bq.w;
    } else {
#pragma unroll
      for (int j = 0; j < 8; ++j) {
        int gt = t0 + tb + j;
        v[j] = (gt < TIN) ? xrow[c * TIN + j] : 0.f;
      }
    }
  };

  float xw[8];
  load_x(0, xw);
#pragma unroll 4
  for (int c = 0; c < CIN; ++c) {
    float xn[8];
    if (c + 1 < CIN) load_x(c + 1, xn);
    float wa[40];
#pragma unroll
    for (int q = 0; q < 10; ++q) {
      float4 wq = *(const float4*)&wl[c * 160 + wv40 + q * 4];
      wa[q * 4 + 0] = wq.x; wa[q * 4 + 1] = wq.y;
      wa[q * 4 + 2] = wq.z; wa[q * 4 + 3] = wq.w;
    }
#pragma unroll
    for (int ff = 0; ff < 8; ++ff) {
#pragma unroll
      for (int k = 0; k < WIN; ++k) {
        float wv = wa[ff * 5 + k];
        acc[ff][0] = fmaf(xw[k + 0], wv, acc[ff][0]);
        acc[ff][1] = fmaf(xw[k + 1], wv, acc[ff][1]);
        acc[ff][2] = fmaf(xw[k + 2], wv, acc[ff][2]);
        acc[ff][3] = fmaf(xw[k + 3], wv, acc[ff][3]);
      }
    }
    if (c + 1 < CIN) {
#pragma unroll
      for (int j = 0; j < 8; ++j) xw[j] = xn[j];
    }
  }

  const bool rowvalid = (tg < 63);
#pragma unroll
  for (int ff = 0; ff < 8; ++ff) {
    float n0 = __shfl_down(acc[ff][0], 1);
    float n1 = __shfl_down(acc[ff][1], 1);
    float n2 = __shfl_down(acc[ff][2], 1);
    float n3 = __shfl_down(acc[ff][3], 1);
    float h[8] = {acc[ff][0], acc[ff][1], acc[ff][2], acc[ff][3], n0, n1, n2, n3};
    float o0 = fmaxf(fmaxf(fmaxf(h[0], h[1]), fmaxf(h[2], h[3])), h[4]);
    float o1 = fmaxf(fmaxf(fmaxf(h[1], h[2]), fmaxf(h[3], h[4])), h[5]);
    float o2 = fmaxf(fmaxf(fmaxf(h[2], h[3]), fmaxf(h[4], h[5])), h[6]);
    float o3 = fmaxf(fmaxf(fmaxf(h[3], h[4]), fmaxf(h[5], h[6])), h[7]);
    const int f = wf0 + ff;
    const int t2b = t0 + tb;
    if (rowvalid && (t2b + 3 < TP2)) {
      *(float4*)&h2[((size_t)b * FILT + f) * TP2 + t2b] = make_float4(o0, o1, o2, o3);
    } else if (rowvalid) {
      float ov[4] = {o0, o1, o2, o3};
#pragma unroll
      for (int j = 0; j < 4; ++j) {
        int t2 = t2b + j;
        if (t2 < TP2) h2[((size_t)b * FILT + f) * TP2 + t2] = ov[j];
      }
    }
  }
}

// ---------------------------------------------------------------------------
// Kernel B: BN stats from h2, fp64 accumulation (frozen precision path).
// Grid (8, 64): block (g, f) reduces b in [8g,8g+8) x all t. 33 MB stream.
// ---------------------------------------------------------------------------
__global__ __launch_bounds__(256) void k_bnstat(
    const float* __restrict__ h2, double* __restrict__ bn_s,
    double* __restrict__ bn_q) {
  const int g = blockIdx.x, f = blockIdx.y;
  const int tid = threadIdx.x;
  double s = 0.0, q = 0.0;
  for (int bl = 0; bl < 8; ++bl) {
    const float* row = h2 + ((size_t)(g * 8 + bl) * FILT + f) * TP2;
    for (int i = tid; i < 510; i += 256) {       // 510 float4 = 2040
      float4 v = *(const float4*)(row + i * 4);
      s += (double)v.x + (double)v.y + (double)v.z + (double)v.w;
      q += (double)v.x * v.x + (double)v.y * v.y +
           (double)v.z * v.z + (double)v.w * v.w;
    }
  }
#pragma unroll
  for (int off = 32; off > 0; off >>= 1) {
    s += __shfl_down(s, off);
    q += __shfl_down(q, off);
  }
  __shared__ double lsd[4], lqd[4];
  if ((tid & 63) == 0) { lsd[tid >> 6] = s; lqd[tid >> 6] = q; }
  __syncthreads();
  if (tid == 0) {
    bn_s[f * 8 + g] = lsd[0] + lsd[1] + lsd[2] + lsd[3];
    bn_q[f * 8 + g] = lqd[0] + lqd[1] + lqd[2] + lqd[3];
  }
}

// ---------------------------------------------------------------------------
// Kernel C: conv2 with inline FP64 BN finalize (frozen precision path:
// fp64 sums -> sqrt -> fold; fp64 conv accumulate + sigmoid + quantize).
// ---------------------------------------------------------------------------
__global__ __launch_bounds__(256) void k_conv2(
    const float* __restrict__ h2, const double* __restrict__ bn_s,
    const double* __restrict__ bn_q, const float* __restrict__ gamma,
    const float* __restrict__ beta, const float* __restrict__ w2,
    const float* __restrict__ b2, int* __restrict__ idxp,
    int* __restrict__ count) {
  __shared__ float hl[FILT * 260];
  __shared__ int hist[DEMB];
  __shared__ double ws2l[FILT * WIN];
  __shared__ double c0l;
  const int b = blockIdx.y;
  const int t0 = blockIdx.x * 256;
  const int tid = threadIdx.x;

  if (tid < 64) {                       // inline BN finalize (redundant/block)
    double s = 0.0, q = 0.0;
#pragma unroll
    for (int g = 0; g < 8; ++g) { s += bn_s[tid * 8 + g]; q += bn_q[tid * 8 + g]; }
    const double N = (double)(BATCH * TP2);
    double mu  = s / N;
    double var = q / N - mu * mu;
    double sc  = (double)gamma[tid] / sqrt(var + 1e-5);
    double sh  = (double)beta[tid] - mu * sc;
    double wsum = 0.0;
#pragma unroll
    for (int k = 0; k < WIN; ++k) {
      double wv = (double)w2[tid * WIN + k];
      ws2l[tid * WIN + k] = sc * wv;
      wsum += wv;
    }
    double part = sh * wsum;
#pragma unroll
    for (int off = 32; off > 0; off >>= 1) part += __shfl_down(part, off);
    if (tid == 0) c0l = part + (double)b2[0];
  }
  for (int i = tid; i < FILT * 260; i += 256) {
    int f = i / 260, o = i - f * 260;
    int gt = t0 + o;
    hl[i] = (gt < TP2) ? h2[((size_t)b * FILT + f) * TP2 + gt] : 0.f;
  }
  hist[tid] = 0;
  __syncthreads();
  const int t = t0 + tid;
  if (t < LOUT) {
    double z = c0l;
    for (int f = 0; f < FILT; ++f) {
      const double* wr = &ws2l[f * WIN];
      z = fma((double)hl[f * 260 + tid + 0], wr[0], z);
      z = fma((double)hl[f * 260 + tid + 1], wr[1], z);
      z = fma((double)hl[f * 260 + tid + 2], wr[2], z);
      z = fma((double)hl[f * 260 + tid + 3], wr[3], z);
      z = fma((double)hl[f * 260 + tid + 4], wr[4], z);
    }
    z = z > 0.0 ? z : 0.0;
    double c = 1.0 / (1.0 + exp(-z));
    int iv = (int)ceil(c * 256.0) - 1;
    iv = min(max(iv, 0), DEMB - 1);
    idxp[b * LOUT + t] = iv;
    atomicAdd(&hist[iv], 1);
  }
  __syncthreads();
  atomicAdd(&count[b * DEMB + tid], hist[tid]);
}

// ---------------------------------------------------------------------------
// Kernel D: S[b,a,j] = sum_{l in chunk: idx[b,l]==j} W1[a,l]. (unchanged)
// ---------------------------------------------------------------------------
__global__ __launch_bounds__(256) void k_sbuild(
    const int* __restrict__ idxp, const float* __restrict__ w1t,
    float* __restrict__ Sg) {
  __shared__ float S[DA * 257];
  __shared__ int il[512];
  const int b = blockIdx.y, ch = blockIdx.x;
  const int tid = threadIdx.x;
  for (int i = tid; i < DA * 257; i += 256) S[i] = 0.f;
  const int l0 = ch * CS;
  for (int i = tid; i < CS; i += 256) il[i] = idxp[b * LOUT + l0 + i];
  __syncthreads();
  const int a = tid & 63, w = tid >> 6;
#pragma unroll 4
  for (int li = w; li < CS; li += 4) {
    int j = il[li];                          // wave-uniform broadcast
    float v = w1t[(l0 + li) * DA + a];       // coalesced 256B/wave
    atomicAdd(&S[a * 257 + j], v);
  }
  __syncthreads();
  for (int i = tid; i < DA * DEMB; i += 256) {
    int aa = i >> 8, j = i & 255;
    Sg[((b * NC + ch) * DA + aa) * DEMB + j] = S[aa * 257 + j];
  }
}

// ---------------------------------------------------------------------------
// Kernel E: fp32 GEMM T = (sum_ch S) @ emb256, epilogue A = sum_a W2 tanh(T).
// ---------------------------------------------------------------------------
__global__ __launch_bounds__(256) void k_gemmA(
    const float* __restrict__ Sg, const float* __restrict__ emb,
    const float* __restrict__ W2, float* __restrict__ Avec) {
  __shared__ float Al[16 * 64];
  __shared__ float Bl[16 * 64];
  __shared__ float red[16 * 64];
  const int b = blockIdx.x, c0 = blockIdx.y * 64;
  const int tid = threadIdx.x;
  const int tx = tid & 15, ty = tid >> 4;
  const int sa = tid >> 2, skq = (tid & 3) * 4;   // A staging map
  const int bk = tid >> 4, bseg = tid & 15;       // B staging map
  float acc[4][4] = {{0}};

  for (int kc = 0; kc < 16; ++kc) {
    const int kb = kc * 16;
    float4 v0 = *(const float4*)&Sg[((b * NC + 0) * DA + sa) * DEMB + kb + skq];
    float4 v1 = *(const float4*)&Sg[((b * NC + 1) * DA + sa) * DEMB + kb + skq];
    float4 v2 = *(const float4*)&Sg[((b * NC + 2) * DA + sa) * DEMB + kb + skq];
    float4 v3 = *(const float4*)&Sg[((b * NC + 3) * DA + sa) * DEMB + kb + skq];
    float4 sv = make_float4(v0.x + v1.x + v2.x + v3.x, v0.y + v1.y + v2.y + v3.y,
                            v0.z + v1.z + v2.z + v3.z, v0.w + v1.w + v2.w + v3.w);
    Al[(skq + 0) * 64 + sa] = sv.x;
    Al[(skq + 1) * 64 + sa] = sv.y;
    Al[(skq + 2) * 64 + sa] = sv.z;
    Al[(skq + 3) * 64 + sa] = sv.w;
    float4 e4 = *(const float4*)&emb[(kb + bk) * DEMB + c0 + bseg * 4];
    *(float4*)&Bl[bk * 64 + bseg * 4] = e4;
    __syncthreads();
#pragma unroll
    for (int k = 0; k < 16; ++k) {
      float4 av = *(const float4*)&Al[k * 64 + ty * 4];
      float4 bv = *(const float4*)&Bl[k * 64 + tx * 4];
      acc[0][0] = fmaf(av.x, bv.x, acc[0][0]); acc[0][1] = fmaf(av.x, bv.y, acc[0][1]);
      acc[0][2] = fmaf(av.x, bv.z, acc[0][2]); acc[0][3] = fmaf(av.x, bv.w, acc[0][3]);
      acc[1][0] = fmaf(av.y, bv.x, acc[1][0]); acc[1][1] = fmaf(av.y, bv.y, acc[1][1]);
      acc[1][2] = fmaf(av.y, bv.z, acc[1][2]); acc[1][3] = fmaf(av.y, bv.w, acc[1][3]);
      acc[2][0] = fmaf(av.z, bv.x, acc[2][0]); acc[2][1] = fmaf(av.z, bv.y, acc[2][1]);
      acc[2][2] = fmaf(av.z, bv.z, acc[2][2]); acc[2][3] = fmaf(av.z, bv.w, acc[2][3]);
      acc[3][0] = fmaf(av.w, bv.x, acc[3][0]); acc[3][1] = fmaf(av.w, bv.y, acc[3][1]);
      acc[3][2] = fmaf(av.w, bv.z, acc[3][2]); acc[3][3] = fmaf(av.w, bv.w, acc[3][3]);
    }
    __syncthreads();
  }
  float cs[4] = {0.f, 0.f, 0.f, 0.f};
#pragma unroll
  for (int r = 0; r < 4; ++r) {
    float wv = W2[ty * 4 + r];
#pragma unroll
    for (int j = 0; j < 4; ++j) cs[j] += tanhf(acc[r][j]) * wv;
  }
#pragma unroll
  for (int j = 0; j < 4; ++j) red[ty * 64 + tx * 4 + j] = cs[j];
  __syncthreads();
  if (tid < 64) {
    float s = 0.f;
#pragma unroll
    for (int q = 0; q < 16; ++q) s += red[q * 64 + tid];
    Avec[b * DEMB + c0 + tid] = s;
  }
}

// ---------------------------------------------------------------------------
// Kernel G: bucket softmax + fused att gather + barrier-free scores
// (per-wave sectors; 22 syncthreads removed vs R4).
// ---------------------------------------------------------------------------
__global__ __launch_bounds__(256) void k_att(
    const float* __restrict__ Avec, const float* __restrict__ embT,
    const int* __restrict__ count, const float* __restrict__ linw,
    const float* __restrict__ linb, const int* __restrict__ idxp,
    float* __restrict__ att, float* __restrict__ scores) {
  __shared__ float Al[DEMB];
  __shared__ float pl[DEMB];
  __shared__ float scratch[4];
  const int b = blockIdx.x, j = threadIdx.x;
  Al[j] = Avec[b * DEMB + j];
  __syncthreads();
  float dot = 0.f;
  for (int d = 0; d < DEMB; ++d) dot = fmaf(embT[d * DEMB + j], Al[d], dot);
  const int cnt = count[b * DEMB + j];
  float v = (cnt > 0) ? dot : -3.4e38f;
#pragma unroll
  for (int off = 32; off > 0; off >>= 1) v = fmaxf(v, __shfl_down(v, off));
  if ((j & 63) == 0) scratch[j >> 6] = v;
  __syncthreads();
  const float m = fmaxf(fmaxf(scratch[0], scratch[1]), fmaxf(scratch[2], scratch[3]));
  __syncthreads();
  float e = (cnt > 0) ? expf(dot - m) : 0.f;
  float zs = e * (float)cnt;
#pragma unroll
  for (int off = 32; off > 0; off >>= 1) zs += __shfl_down(zs, off);
  if ((j & 63) == 0) scratch[j >> 6] = zs;
  __syncthreads();
  const float Z = scratch[0] + scratch[1] + scratch[2] + scratch[3];
  pl[j] = (cnt > 0) ? e / Z : 0.f;
  __syncthreads();
  // fused gather
  for (int l = j; l < LOUT; l += 256)
    att[b * LOUT + l] = pl[idxp[b * LOUT + l]];
  // scores: wave w -> sectors w, w+4, w+8 (no barriers; Al already synced)
  const int w = j >> 6, lane = j & 63;
  for (int s = w; s < NSEC; s += 4) {
    float part = 0.f;
#pragma unroll
    for (int r = 0; r < 4; ++r)
      part = fmaf(Al[lane + r * 64], linw[s * DEMB + lane + r * 64], part);
#pragma unroll
    for (int off = 32; off > 0; off >>= 1) part += __shfl_down(part, off);
    if (lane == 0) scores[b * NSEC + s] = part + linb[s];
  }
}

// ---------------------------------------------------------------------------
extern "C" void kernel_launch(void* const* d_in, const int* in_sizes, int n_in,
                              void* d_out, int out_size, void* d_ws, size_t ws_size,
                              hipStream_t stream) {
  const float* x      = (const float*)d_in[0];
  const float* w1     = (const float*)d_in[1];
  const float* b1     = (const float*)d_in[2];
  const float* gamma  = (const float*)d_in[3];
  const float* beta   = (const float*)d_in[4];
  const float* w2     = (const float*)d_in[5];
  const float* b2     = (const float*)d_in[6];
  const float* emb    = (const float*)d_in[7];
  const float* W1     = (const float*)d_in[8];
  const float* W2     = (const float*)d_in[9];
  const float* linw   = (const float*)d_in[10];
  const float* linb   = (const float*)d_in[11];

  char* ws = (char*)d_ws;
  int*    count = (int*)   (ws + 0);           // 65536
  double* bn_s  = (double*)(ws + 65536);       // 512 d -> 69632
  double* bn_q  = (double*)(ws + 69632);       // -> 73728
  int*    idxp  = (int*)   (ws + 73728);       // -> 594944
  float*  w1t   = (float*) (ws + 594944);      // -> 1116160
  float*  embT  = (float*) (ws + 1116160);     // -> 1378304
  float*  Avec  = (float*) (ws + 1378304);     // -> 1443840
  float*  w1r   = (float*) (ws + 1443840);     // -> 1484800
  float*  h2    = (float*) (ws + 1484800);     // -> 34908160
  float*  Sg    = (float*) (ws + 34908160);    // -> 51685376

  float* att_out    = (float*)d_out;
  float* scores_out = (float*)d_out + BATCH * LOUT;

  k_prep<<<dim3(152), 256, 0, stream>>>(W1, emb, w1, w1t, embT, w1r, count);
  k_conv1pool<<<dim3(9, 64, 2), 256, 0, stream>>>(x, w1r, b1, h2);
  k_bnstat<<<dim3(8, 64), 256, 0, stream>>>(h2, bn_s, bn_q);
  k_conv2<<<dim3(8, 64), 256, 0, stream>>>(h2, bn_s, bn_q, gamma, beta, w2, b2,
                                           idxp, count);
  k_sbuild<<<dim3(NC, 64), 256, 0, stream>>>(idxp, w1t, Sg);
  k_gemmA<<<dim3(64, 4), 256, 0, stream>>>(Sg, emb, W2, Avec);
  k_att<<<dim3(64), 256, 0, stream>>>(Avec, embT, count, linw, linb, idxp,
                                      att_out, scores_out);
}

// Round 6
// 331.640 us; speedup vs baseline: 1.1368x; 1.0440x over previous
//
#include <hip/hip_runtime.h>
#include <hip/hip_bf16.h>
#include <math.h>

// Problem constants
#define BATCH 64
#define CIN   32
#define TIN   2048
#define FILT  64
#define WIN   5
#define TP1   2044   // conv1 out
#define TP2   2040   // pool out
#define LOUT  2036   // conv2 out
#define DEMB  256
#define DA    64
#define NSEC  11
#define NC    4      // S chunks
#define CS    509    // l's per chunk (4*509 = 2036)
#define CT_TILE 504  // pool outputs per conv1 block (63 lanes x 8)

// ---------------------------------------------------------------------------
// Kernel P: fused prep — zero count, W1 transpose, emb transpose, w1 repack.
// ---------------------------------------------------------------------------
__global__ __launch_bounds__(256) void k_prep(
    const float* __restrict__ W1, const float* __restrict__ emb,
    const float* __restrict__ w1, float* __restrict__ w1t,
    float* __restrict__ embT, float* __restrict__ w1r, int* __restrict__ count) {
  __shared__ float tl[64 * 65];
  int bk = blockIdx.x;
  const int tid = threadIdx.x;
  if (bk < 64) { count[bk * 256 + tid] = 0; return; }
  bk -= 64;
  if (bk < 32) {                       // W1 [64 x 2036] -> w1t [2036 x 64]
    const int l0 = bk * 64;
    const int lc = tid & 63, rq = tid >> 6;
    for (int a = rq; a < 64; a += 4)
      tl[a * 65 + lc] = (l0 + lc < LOUT) ? W1[a * LOUT + l0 + lc] : 0.f;
    __syncthreads();
    for (int lp = rq; lp < 64; lp += 4)
      if (l0 + lp < LOUT) w1t[(l0 + lp) * 64 + lc] = tl[lc * 65 + lp];
    return;
  }
  bk -= 32;
  if (bk < 16) {                       // emb [256 x 256] -> embT [256 x 256]
    const int j0 = (bk & 3) * 64, d0 = (bk >> 2) * 64;
    const int c = tid & 63, rq = tid >> 6;
    for (int j = rq; j < 64; j += 4) tl[j * 65 + c] = emb[(j0 + j) * DEMB + d0 + c];
    __syncthreads();
    for (int d = rq; d < 64; d += 4) embT[(d0 + d) * DEMB + j0 + c] = tl[c * 65 + d];
    return;
  }
  bk -= 16;
  {                                    // w1 [f][c][k] -> w1r [c][f*5+k]
    int i = bk * 256 + tid;            // 40*256 = 10240 exactly
    int c = i / 320, r = i - c * 320, f = r / 5, k = r - f * 5;
    w1r[i] = w1[f * (CIN * WIN) + c * WIN + k];
  }
}

// ---------------------------------------------------------------------------
// Kernel A: conv1 + bias + maxpool(5,1). R6: 4 filters/wave (z-split 4-way),
// 8 outputs/lane -> per c: 160 FMA, 5 ds_read_b128 (immediate-use, no wa[]
// buffer), 3 global b128. No prefetch, no unroll pragma (R5's VGPR balloon
// reverted; R4 precedent: compiler keeps this tight). Grid (5, 64, 4).
// ---------------------------------------------------------------------------
__global__ __launch_bounds__(256) void k_conv1pool(
    const float* __restrict__ x, const float* __restrict__ w1r,
    const float* __restrict__ b1, float* __restrict__ h2) {
  __shared__ float wl[CIN * 80];
  const int b   = blockIdx.y;
  const int t0  = blockIdx.x * CT_TILE;
  const int tid = threadIdx.x;
  const int z   = blockIdx.z;

  for (int i = tid; i < CIN * 80; i += 256) {
    int c = i >> 6 >> 1 ? 0 : 0, cc = i / 80, r = i - cc * 80;
    (void)c;
    wl[i] = w1r[cc * 320 + z * 80 + r];
  }
  __syncthreads();

  const int tg   = tid & 63;
  const int tb   = tg * 8;
  const int wv20 = (tid >> 6) * 20;
  const int wf0  = __builtin_amdgcn_readfirstlane(z * 16 + (tid >> 6) * 4);

  float acc[4][8];
#pragma unroll
  for (int ff = 0; ff < 4; ++ff) {
    float bias = b1[wf0 + ff];
#pragma unroll
    for (int j = 0; j < 8; ++j) acc[ff][j] = bias;
  }

  const float* xrow = x + (size_t)b * CIN * TIN + t0 + tb;
  const bool safe = (t0 + tb + 12) <= TIN;

  for (int c = 0; c < CIN; ++c) {
    float xw[12];
    if (safe) {
      float4 a0 = *(const float4*)(xrow + c * TIN);
      float4 a1 = *(const float4*)(xrow + c * TIN + 4);
      float4 a2 = *(const float4*)(xrow + c * TIN + 8);
      xw[0] = a0.x; xw[1] = a0.y; xw[2]  = a0.z; xw[3]  = a0.w;
      xw[4] = a1.x; xw[5] = a1.y; xw[6]  = a1.z; xw[7]  = a1.w;
      xw[8] = a2.x; xw[9] = a2.y; xw[10] = a2.z; xw[11] = a2.w;
    } else {
#pragma unroll
      for (int j = 0; j < 12; ++j) {
        int gt = t0 + tb + j;
        xw[j] = (gt < TIN) ? xrow[c * TIN + j] : 0.f;
      }
    }
#pragma unroll
    for (int q = 0; q < 5; ++q) {
      float4 wq = *(const float4*)&wl[c * 80 + wv20 + q * 4];
      float wv[4] = {wq.x, wq.y, wq.z, wq.w};
#pragma unroll
      for (int r = 0; r < 4; ++r) {
        const int wi = q * 4 + r;          // compile-time
        const int ff = wi / 5, k = wi % 5; // static decode
#pragma unroll
        for (int j = 0; j < 8; ++j)
          acc[ff][j] = fmaf(xw[k + j], wv[r], acc[ff][j]);
      }
    }
  }

  const bool lanevalid = (tg < 63);
#pragma unroll
  for (int ff = 0; ff < 4; ++ff) {
    float n0 = __shfl_down(acc[ff][0], 1);
    float n1 = __shfl_down(acc[ff][1], 1);
    float n2 = __shfl_down(acc[ff][2], 1);
    float n3 = __shfl_down(acc[ff][3], 1);
    float h[12] = {acc[ff][0], acc[ff][1], acc[ff][2], acc[ff][3],
                   acc[ff][4], acc[ff][5], acc[ff][6], acc[ff][7],
                   n0, n1, n2, n3};
    float o[8];
#pragma unroll
    for (int j = 0; j < 8; ++j) {
      float m = fmaxf(fmaxf(h[j], h[j + 1]), fmaxf(h[j + 2], h[j + 3]));
      o[j] = fmaxf(m, h[j + 4]);
    }
    const int f = wf0 + ff;
    const int t2b = t0 + tb;
    if (lanevalid && (t2b + 7 < TP2)) {
      float* dst = &h2[((size_t)b * FILT + f) * TP2 + t2b];
      *(float4*)dst = make_float4(o[0], o[1], o[2], o[3]);
      *(float4*)(dst + 4) = make_float4(o[4], o[5], o[6], o[7]);
    } else if (lanevalid) {
#pragma unroll
      for (int j = 0; j < 8; ++j) {
        int t2 = t2b + j;
        if (t2 < TP2) h2[((size_t)b * FILT + f) * TP2 + t2] = o[j];
      }
    }
  }
}

// ---------------------------------------------------------------------------
// Kernel B: BN stats from h2, fp64 accumulation (frozen precision path).
// ---------------------------------------------------------------------------
__global__ __launch_bounds__(256) void k_bnstat(
    const float* __restrict__ h2, double* __restrict__ bn_s,
    double* __restrict__ bn_q) {
  const int g = blockIdx.x, f = blockIdx.y;
  const int tid = threadIdx.x;
  double s = 0.0, q = 0.0;
  for (int bl = 0; bl < 8; ++bl) {
    const float* row = h2 + ((size_t)(g * 8 + bl) * FILT + f) * TP2;
    for (int i = tid; i < 510; i += 256) {       // 510 float4 = 2040
      float4 v = *(const float4*)(row + i * 4);
      s += (double)v.x + (double)v.y + (double)v.z + (double)v.w;
      q += (double)v.x * v.x + (double)v.y * v.y +
           (double)v.z * v.z + (double)v.w * v.w;
    }
  }
#pragma unroll
  for (int off = 32; off > 0; off >>= 1) {
    s += __shfl_down(s, off);
    q += __shfl_down(q, off);
  }
  __shared__ double lsd[4], lqd[4];
  if ((tid & 63) == 0) { lsd[tid >> 6] = s; lqd[tid >> 6] = q; }
  __syncthreads();
  if (tid == 0) {
    bn_s[f * 8 + g] = lsd[0] + lsd[1] + lsd[2] + lsd[3];
    bn_q[f * 8 + g] = lqd[0] + lqd[1] + lqd[2] + lqd[3];
  }
}

// ---------------------------------------------------------------------------
// Kernel C: conv2 with inline FP64 BN finalize (frozen precision path).
// ---------------------------------------------------------------------------
__global__ __launch_bounds__(256) void k_conv2(
    const float* __restrict__ h2, const double* __restrict__ bn_s,
    const double* __restrict__ bn_q, const float* __restrict__ gamma,
    const float* __restrict__ beta, const float* __restrict__ w2,
    const float* __restrict__ b2, int* __restrict__ idxp,
    int* __restrict__ count) {
  __shared__ float hl[FILT * 260];
  __shared__ int hist[DEMB];
  __shared__ double ws2l[FILT * WIN];
  __shared__ double c0l;
  const int b = blockIdx.y;
  const int t0 = blockIdx.x * 256;
  const int tid = threadIdx.x;

  if (tid < 64) {                       // inline BN finalize (redundant/block)
    double s = 0.0, q = 0.0;
#pragma unroll
    for (int g = 0; g < 8; ++g) { s += bn_s[tid * 8 + g]; q += bn_q[tid * 8 + g]; }
    const double N = (double)(BATCH * TP2);
    double mu  = s / N;
    double var = q / N - mu * mu;
    double sc  = (double)gamma[tid] / sqrt(var + 1e-5);
    double sh  = (double)beta[tid] - mu * sc;
    double wsum = 0.0;
#pragma unroll
    for (int k = 0; k < WIN; ++k) {
      double wv = (double)w2[tid * WIN + k];
      ws2l[tid * WIN + k] = sc * wv;
      wsum += wv;
    }
    double part = sh * wsum;
#pragma unroll
    for (int off = 32; off > 0; off >>= 1) part += __shfl_down(part, off);
    if (tid == 0) c0l = part + (double)b2[0];
  }
  for (int i = tid; i < FILT * 260; i += 256) {
    int f = i / 260, o = i - f * 260;
    int gt = t0 + o;
    hl[i] = (gt < TP2) ? h2[((size_t)b * FILT + f) * TP2 + gt] : 0.f;
  }
  hist[tid] = 0;
  __syncthreads();
  const int t = t0 + tid;
  if (t < LOUT) {
    double z = c0l;
    for (int f = 0; f < FILT; ++f) {
      const double* wr = &ws2l[f * WIN];
      z = fma((double)hl[f * 260 + tid + 0], wr[0], z);
      z = fma((double)hl[f * 260 + tid + 1], wr[1], z);
      z = fma((double)hl[f * 260 + tid + 2], wr[2], z);
      z = fma((double)hl[f * 260 + tid + 3], wr[3], z);
      z = fma((double)hl[f * 260 + tid + 4], wr[4], z);
    }
    z = z > 0.0 ? z : 0.0;
    double c = 1.0 / (1.0 + exp(-z));
    int iv = (int)ceil(c * 256.0) - 1;
    iv = min(max(iv, 0), DEMB - 1);
    idxp[b * LOUT + t] = iv;
    atomicAdd(&hist[iv], 1);
  }
  __syncthreads();
  atomicAdd(&count[b * DEMB + tid], hist[tid]);
}

// ---------------------------------------------------------------------------
// Kernel D: S[b,a,j] = sum_{l in chunk: idx[b,l]==j} W1[a,l]. (unchanged)
// ---------------------------------------------------------------------------
__global__ __launch_bounds__(256) void k_sbuild(
    const int* __restrict__ idxp, const float* __restrict__ w1t,
    float* __restrict__ Sg) {
  __shared__ float S[DA * 257];
  __shared__ int il[512];
  const int b = blockIdx.y, ch = blockIdx.x;
  const int tid = threadIdx.x;
  for (int i = tid; i < DA * 257; i += 256) S[i] = 0.f;
  const int l0 = ch * CS;
  for (int i = tid; i < CS; i += 256) il[i] = idxp[b * LOUT + l0 + i];
  __syncthreads();
  const int a = tid & 63, w = tid >> 6;
#pragma unroll 4
  for (int li = w; li < CS; li += 4) {
    int j = il[li];                          // wave-uniform broadcast
    float v = w1t[(l0 + li) * DA + a];       // coalesced 256B/wave
    atomicAdd(&S[a * 257 + j], v);
  }
  __syncthreads();
  for (int i = tid; i < DA * DEMB; i += 256) {
    int aa = i >> 8, j = i & 255;
    Sg[((b * NC + ch) * DA + aa) * DEMB + j] = S[aa * 257 + j];
  }
}

// ---------------------------------------------------------------------------
// Kernel E: fp32 GEMM T = (sum_ch S) @ emb256, epilogue A = sum_a W2 tanh(T).
// ---------------------------------------------------------------------------
__global__ __launch_bounds__(256) void k_gemmA(
    const float* __restrict__ Sg, const float* __restrict__ emb,
    const float* __restrict__ W2, float* __restrict__ Avec) {
  __shared__ float Al[16 * 64];
  __shared__ float Bl[16 * 64];
  __shared__ float red[16 * 64];
  const int b = blockIdx.x, c0 = blockIdx.y * 64;
  const int tid = threadIdx.x;
  const int tx = tid & 15, ty = tid >> 4;
  const int sa = tid >> 2, skq = (tid & 3) * 4;   // A staging map
  const int bk = tid >> 4, bseg = tid & 15;       // B staging map
  float acc[4][4] = {{0}};

  for (int kc = 0; kc < 16; ++kc) {
    const int kb = kc * 16;
    float4 v0 = *(const float4*)&Sg[((b * NC + 0) * DA + sa) * DEMB + kb + skq];
    float4 v1 = *(const float4*)&Sg[((b * NC + 1) * DA + sa) * DEMB + kb + skq];
    float4 v2 = *(const float4*)&Sg[((b * NC + 2) * DA + sa) * DEMB + kb + skq];
    float4 v3 = *(const float4*)&Sg[((b * NC + 3) * DA + sa) * DEMB + kb + skq];
    float4 sv = make_float4(v0.x + v1.x + v2.x + v3.x, v0.y + v1.y + v2.y + v3.y,
                            v0.z + v1.z + v2.z + v3.z, v0.w + v1.w + v2.w + v3.w);
    Al[(skq + 0) * 64 + sa] = sv.x;
    Al[(skq + 1) * 64 + sa] = sv.y;
    Al[(skq + 2) * 64 + sa] = sv.z;
    Al[(skq + 3) * 64 + sa] = sv.w;
    float4 e4 = *(const float4*)&emb[(kb + bk) * DEMB + c0 + bseg * 4];
    *(float4*)&Bl[bk * 64 + bseg * 4] = e4;
    __syncthreads();
#pragma unroll
    for (int k = 0; k < 16; ++k) {
      float4 av = *(const float4*)&Al[k * 64 + ty * 4];
      float4 bv = *(const float4*)&Bl[k * 64 + tx * 4];
      acc[0][0] = fmaf(av.x, bv.x, acc[0][0]); acc[0][1] = fmaf(av.x, bv.y, acc[0][1]);
      acc[0][2] = fmaf(av.x, bv.z, acc[0][2]); acc[0][3] = fmaf(av.x, bv.w, acc[0][3]);
      acc[1][0] = fmaf(av.y, bv.x, acc[1][0]); acc[1][1] = fmaf(av.y, bv.y, acc[1][1]);
      acc[1][2] = fmaf(av.y, bv.z, acc[1][2]); acc[1][3] = fmaf(av.y, bv.w, acc[1][3]);
      acc[2][0] = fmaf(av.z, bv.x, acc[2][0]); acc[2][1] = fmaf(av.z, bv.y, acc[2][1]);
      acc[2][2] = fmaf(av.z, bv.z, acc[2][2]); acc[2][3] = fmaf(av.z, bv.w, acc[2][3]);
      acc[3][0] = fmaf(av.w, bv.x, acc[3][0]); acc[3][1] = fmaf(av.w, bv.y, acc[3][1]);
      acc[3][2] = fmaf(av.w, bv.z, acc[3][2]); acc[3][3] = fmaf(av.w, bv.w, acc[3][3]);
    }
    __syncthreads();
  }
  float cs[4] = {0.f, 0.f, 0.f, 0.f};
#pragma unroll
  for (int r = 0; r < 4; ++r) {
    float wv = W2[ty * 4 + r];
#pragma unroll
    for (int j = 0; j < 4; ++j) cs[j] += tanhf(acc[r][j]) * wv;
  }
#pragma unroll
  for (int j = 0; j < 4; ++j) red[ty * 64 + tx * 4 + j] = cs[j];
  __syncthreads();
  if (tid < 64) {
    float s = 0.f;
#pragma unroll
    for (int q = 0; q < 16; ++q) s += red[q * 64 + tid];
    Avec[b * DEMB + c0 + tid] = s;
  }
}

// ---------------------------------------------------------------------------
// Kernel G: bucket softmax + fused att gather + barrier-free scores.
// ---------------------------------------------------------------------------
__global__ __launch_bounds__(256) void k_att(
    const float* __restrict__ Avec, const float* __restrict__ embT,
    const int* __restrict__ count, const float* __restrict__ linw,
    const float* __restrict__ linb, const int* __restrict__ idxp,
    float* __restrict__ att, float* __restrict__ scores) {
  __shared__ float Al[DEMB];
  __shared__ float pl[DEMB];
  __shared__ float scratch[4];
  const int b = blockIdx.x, j = threadIdx.x;
  Al[j] = Avec[b * DEMB + j];
  __syncthreads();
  float dot = 0.f;
  for (int d = 0; d < DEMB; ++d) dot = fmaf(embT[d * DEMB + j], Al[d], dot);
  const int cnt = count[b * DEMB + j];
  float v = (cnt > 0) ? dot : -3.4e38f;
#pragma unroll
  for (int off = 32; off > 0; off >>= 1) v = fmaxf(v, __shfl_down(v, off));
  if ((j & 63) == 0) scratch[j >> 6] = v;
  __syncthreads();
  const float m = fmaxf(fmaxf(scratch[0], scratch[1]), fmaxf(scratch[2], scratch[3]));
  __syncthreads();
  float e = (cnt > 0) ? expf(dot - m) : 0.f;
  float zs = e * (float)cnt;
#pragma unroll
  for (int off = 32; off > 0; off >>= 1) zs += __shfl_down(zs, off);
  if ((j & 63) == 0) scratch[j >> 6] = zs;
  __syncthreads();
  const float Z = scratch[0] + scratch[1] + scratch[2] + scratch[3];
  pl[j] = (cnt > 0) ? e / Z : 0.f;
  __syncthreads();
  for (int l = j; l < LOUT; l += 256)
    att[b * LOUT + l] = pl[idxp[b * LOUT + l]];
  const int w = j >> 6, lane = j & 63;
  for (int s = w; s < NSEC; s += 4) {
    float part = 0.f;
#pragma unroll
    for (int r = 0; r < 4; ++r)
      part = fmaf(Al[lane + r * 64], linw[s * DEMB + lane + r * 64], part);
#pragma unroll
    for (int off = 32; off > 0; off >>= 1) part += __shfl_down(part, off);
    if (lane == 0) scores[b * NSEC + s] = part + linb[s];
  }
}

// ---------------------------------------------------------------------------
extern "C" void kernel_launch(void* const* d_in, const int* in_sizes, int n_in,
                              void* d_out, int out_size, void* d_ws, size_t ws_size,
                              hipStream_t stream) {
  const float* x      = (const float*)d_in[0];
  const float* w1     = (const float*)d_in[1];
  const float* b1     = (const float*)d_in[2];
  const float* gamma  = (const float*)d_in[3];
  const float* beta   = (const float*)d_in[4];
  const float* w2     = (const float*)d_in[5];
  const float* b2     = (const float*)d_in[6];
  const float* emb    = (const float*)d_in[7];
  const float* W1     = (const float*)d_in[8];
  const float* W2     = (const float*)d_in[9];
  const float* linw   = (const float*)d_in[10];
  const float* linb   = (const float*)d_in[11];

  char* ws = (char*)d_ws;
  int*    count = (int*)   (ws + 0);           // 65536
  double* bn_s  = (double*)(ws + 65536);       // -> 69632
  double* bn_q  = (double*)(ws + 69632);       // -> 73728
  int*    idxp  = (int*)   (ws + 73728);       // -> 594944
  float*  w1t   = (float*) (ws + 594944);      // -> 1116160
  float*  embT  = (float*) (ws + 1116160);     // -> 1378304
  float*  Avec  = (float*) (ws + 1378304);     // -> 1443840
  float*  w1r   = (float*) (ws + 1443840);     // -> 1484800
  float*  h2    = (float*) (ws + 1484800);     // -> 34908160
  float*  Sg    = (float*) (ws + 34908160);    // -> 51685376

  float* att_out    = (float*)d_out;
  float* scores_out = (float*)d_out + BATCH * LOUT;

  k_prep<<<dim3(152), 256, 0, stream>>>(W1, emb, w1, w1t, embT, w1r, count);
  k_conv1pool<<<dim3(5, 64, 4), 256, 0, stream>>>(x, w1r, b1, h2);
  k_bnstat<<<dim3(8, 64), 256, 0, stream>>>(h2, bn_s, bn_q);
  k_conv2<<<dim3(8, 64), 256, 0, stream>>>(h2, bn_s, bn_q, gamma, beta, w2, b2,
                                           idxp, count);
  k_sbuild<<<dim3(NC, 64), 256, 0, stream>>>(idxp, w1t, Sg);
  k_gemmA<<<dim3(64, 4), 256, 0, stream>>>(Sg, emb, W2, Avec);
  k_att<<<dim3(64), 256, 0, stream>>>(Avec, embT, count, linw, linb, idxp,
                                      att_out, scores_out);
}